// Round 1
// baseline (208.253 us; speedup 1.0000x reference)
//
#include <hip/hip_runtime.h>
#include <hip/hip_bf16.h>
#include <cstdint>

#define DIM   1024
#define KEY   128
#define UV    1024
#define NCOL  (UV*2 + KEY)   // 2176
#define SEQ   2048
#define BATCH 4
#define MTOT  (BATCH*SEQ)    // 8192
#define SCALE 0.08838834764831845f  // 1/sqrt(128)

typedef __attribute__((ext_vector_type(8))) short short8;
typedef __attribute__((ext_vector_type(4))) float f32x4;

__device__ inline unsigned short f2b(float x) {
  unsigned int u = __float_as_uint(x);
  unsigned int r = (u + 0x7fffu + ((u >> 16) & 1u)) >> 16;
  return (unsigned short)r;
}
__device__ inline float b2f(unsigned short x) {
  return __uint_as_float(((unsigned int)x) << 16);
}

__device__ inline void gload_lds16(const void* g, void* l) {
  __builtin_amdgcn_global_load_lds(
      (const __attribute__((address_space(1))) unsigned int*)g,
      (__attribute__((address_space(3))) unsigned int*)l, 16, 0, 0);
}

// ---------------------------------------------------------------------------
// Shared 128x128 bt-GEMM tile: C[m][n] = sum_k A[m][k] * Bt[n][k]   (bf16 in,
// f32 acc).  m97 structure: BK=32, 4 waves (2x2), 16x16x32 MFMA, width-16
// global_load_lds staging, 2-barrier K loop.
// A points at row m0 (k=0), Bt at row n0.  K = reduction length.
// ---------------------------------------------------------------------------
__device__ inline void mfma_tile_bt(const unsigned short* __restrict__ A,
                                    const unsigned short* __restrict__ Bt,
                                    int K, f32x4 acc[4][4],
                                    unsigned short* ldsA, unsigned short* ldsB) {
  const int tid  = threadIdx.x;
  const int lane = tid & 63;
  const int wid  = tid >> 6;
  const int wr   = wid >> 1, wc = wid & 1;
  const int fr   = lane & 15;
  const int fq   = lane >> 4;

#pragma unroll
  for (int i = 0; i < 4; ++i)
#pragma unroll
    for (int j = 0; j < 4; ++j) acc[i][j] = (f32x4){0.f, 0.f, 0.f, 0.f};

  for (int k0 = 0; k0 < K; k0 += 32) {
    __syncthreads();
#pragma unroll
    for (int i = 0; i < 2; ++i) {
      int c   = i * 256 + tid;        // 0..511 chunk id (16B each)
      int row = c >> 2;
      int kc  = (c & 3) * 8;
      int basechunk = i * 256 + wid * 64;  // wave-uniform LDS base
      gload_lds16(A  + (size_t)row * K + k0 + kc, ldsA + (size_t)basechunk * 8);
      gload_lds16(Bt + (size_t)row * K + k0 + kc, ldsB + (size_t)basechunk * 8);
    }
    __syncthreads();

    short8 af[4], bf[4];
#pragma unroll
    for (int s = 0; s < 4; ++s) {
      af[s] = *(const short8*)&ldsA[(wr * 64 + s * 16 + fr) * 32 + fq * 8];
      bf[s] = *(const short8*)&ldsB[(wc * 64 + s * 16 + fr) * 32 + fq * 8];
    }
#pragma unroll
    for (int i = 0; i < 4; ++i)
#pragma unroll
      for (int j = 0; j < 4; ++j)
        acc[i][j] = __builtin_amdgcn_mfma_f32_16x16x32_bf16(af[i], bf[j], acc[i][j], 0, 0, 0);
  }
}

// C/D mapping: row = wr*64 + i*16 + fq*4 + r ; col = wc*64 + j*16 + fr
#define EPILOGUE_COORDS()                      \
  const int lane = threadIdx.x & 63;           \
  const int wid  = threadIdx.x >> 6;           \
  const int wr   = wid >> 1, wc = wid & 1;     \
  const int fr   = lane & 15;                  \
  const int fq   = lane >> 4;

// ---------------------------------------------------------------------------
// helper kernels
// ---------------------------------------------------------------------------
__global__ __launch_bounds__(256) void k_cvt(const float* __restrict__ in,
                                             unsigned short* __restrict__ out) {
  int id = blockIdx.x * 256 + threadIdx.x;   // over n/4 elements
  float4 f = ((const float4*)in)[id];
  ushort4 o;
  o.x = f2b(f.x); o.y = f2b(f.y); o.z = f2b(f.z); o.w = f2b(f.w);
  ((ushort4*)out)[id] = o;
}

// out[c][r] = bf16(in[r][c]);  R,C multiples of 32; block (32,8)
__global__ void k_tcvt(const float* __restrict__ in, unsigned short* __restrict__ out,
                       int R, int C) {
  __shared__ float t[32][33];
  int c0 = blockIdx.x * 32, r0 = blockIdx.y * 32;
  int tx = threadIdx.x, ty = threadIdx.y;
#pragma unroll
  for (int i = 0; i < 4; ++i)
    t[ty + i * 8][tx] = in[(size_t)(r0 + ty + i * 8) * C + c0 + tx];
  __syncthreads();
#pragma unroll
  for (int i = 0; i < 4; ++i)
    out[(size_t)(c0 + ty + i * 8) * R + r0 + tx] = f2b(t[tx][ty + i * 8]);
}

__global__ __launch_bounds__(256) void k_masksum(const int* __restrict__ mask,
                                                 float* __restrict__ ll) {
  int wid = threadIdx.x >> 6, lane = threadIdx.x & 63;
  int row = blockIdx.x * 4 + wid;
  const int4* p = (const int4*)(mask + (size_t)row * SEQ);
  int s = 0;
#pragma unroll
  for (int i = 0; i < 8; ++i) { int4 v = p[lane + 64 * i]; s += v.x + v.y + v.z + v.w; }
  for (int off = 32; off; off >>= 1) s += __shfl_down(s, off);
  if (lane == 0) ll[row] = (float)s;
}

__global__ __launch_bounds__(256) void k_rope(const float* __restrict__ qk,
                                              const float* __restrict__ sn,
                                              const float* __restrict__ cs,
                                              const float* __restrict__ qg,
                                              const float* __restrict__ qb,
                                              const float* __restrict__ kg,
                                              const float* __restrict__ kb,
                                              unsigned short* __restrict__ q,
                                              unsigned short* __restrict__ k) {
  int id = blockIdx.x * 256 + threadIdx.x;  // over 8192*64
  int m = id >> 6, t = id & 63;
  int n = m & (SEQ - 1);
  float x1 = qk[m * KEY + 2 * t], x2 = qk[m * KEY + 2 * t + 1];
  float s_ = sn[n * 64 + t], c_ = cs[n * 64 + t];
  float a1 = x1 * qg[2 * t] + qb[2 * t];
  float a2 = x2 * qg[2 * t + 1] + qb[2 * t + 1];
  q[m * KEY + t]      = f2b(a1 * c_ - a2 * s_);
  q[m * KEY + 64 + t] = f2b(a1 * s_ + a2 * c_);
  float b1 = x1 * kg[2 * t] + kb[2 * t];
  float b2 = x2 * kg[2 * t + 1] + kb[2 * t + 1];
  k[m * KEY + t]      = f2b(b1 * c_ - b2 * s_);
  k[m * KEY + 64 + t] = f2b(b1 * s_ + b2 * c_);
}

// v [MTOT][UV] bf16 -> vT [BATCH][UV][SEQ]
__global__ __launch_bounds__(256) void k_vT(const unsigned short* __restrict__ v,
                                            unsigned short* __restrict__ vT) {
  __shared__ unsigned short t[64][65];
  int b = blockIdx.z;
  int n0 = blockIdx.x * 64;
  int d0 = blockIdx.y * 64;
  int tid = threadIdx.x;
  int r = tid >> 4;
  int c4 = (tid & 15) * 4;
#pragma unroll
  for (int i = 0; i < 4; ++i) {
    int n = n0 + r + i * 16;
    ushort4 val = *(const ushort4*)&v[((size_t)b * SEQ + n) * UV + d0 + c4];
    t[c4 + 0][r + i * 16] = val.x;
    t[c4 + 1][r + i * 16] = val.y;
    t[c4 + 2][r + i * 16] = val.z;
    t[c4 + 3][r + i * 16] = val.w;
  }
  __syncthreads();
#pragma unroll
  for (int i = 0; i < 4; ++i) {
    int d = d0 + r + i * 16;
    ushort4 o;
    o.x = t[r + i * 16][c4 + 0];
    o.y = t[r + i * 16][c4 + 1];
    o.z = t[r + i * 16][c4 + 2];
    o.w = t[r + i * 16][c4 + 3];
    *(ushort4*)&vT[((size_t)b * UV + d) * SEQ + n0 + c4] = o;
  }
}

// ---------------------------------------------------------------------------
// GEMM kernels
// ---------------------------------------------------------------------------
__global__ __launch_bounds__(256) void k_gemm1(const unsigned short* __restrict__ hbf,
                                               const unsigned short* __restrict__ WiT,
                                               const float* __restrict__ bi,
                                               unsigned short* __restrict__ u,
                                               unsigned short* __restrict__ v,
                                               float* __restrict__ qk) {
  __shared__ unsigned short ldsA[128 * 32], ldsB[128 * 32];
  int m0 = blockIdx.x * 128, n0 = blockIdx.y * 128;
  f32x4 acc[4][4];
  mfma_tile_bt(hbf + (size_t)m0 * DIM, WiT + (size_t)n0 * DIM, DIM, acc, ldsA, ldsB);
  EPILOGUE_COORDS();
#pragma unroll
  for (int i = 0; i < 4; ++i)
#pragma unroll
    for (int j = 0; j < 4; ++j)
#pragma unroll
      for (int r = 0; r < 4; ++r) {
        int row = m0 + wr * 64 + i * 16 + fq * 4 + r;
        int col = n0 + wc * 64 + j * 16 + fr;
        float x = acc[i][j][r] + bi[col];
        float s = x / (1.f + __expf(-x));
        if (col < UV)            u[(size_t)row * UV + col] = f2b(s);
        else if (col < 2 * UV)   v[(size_t)row * UV + col - UV] = f2b(s);
        else                     qk[(size_t)row * KEY + col - 2 * UV] = s;
      }
}

__global__ __launch_bounds__(256) void k_qk(const unsigned short* __restrict__ q,
                                            const unsigned short* __restrict__ k,
                                            const int* __restrict__ mask,
                                            const float* __restrict__ ll,
                                            unsigned short* __restrict__ Abuf) {
  __shared__ unsigned short ldsA[128 * 32], ldsB[128 * 32];
  int b = blockIdx.z;
  int m0 = blockIdx.x * 128, n0 = blockIdx.y * 128;
  f32x4 acc[4][4];
  mfma_tile_bt(q + ((size_t)b * SEQ + m0) * KEY, k + ((size_t)b * SEQ + n0) * KEY,
               KEY, acc, ldsA, ldsB);
  EPILOGUE_COORDS();
#pragma unroll
  for (int i = 0; i < 4; ++i)
#pragma unroll
    for (int j = 0; j < 4; ++j)
#pragma unroll
      for (int r = 0; r < 4; ++r) {
        int row = m0 + wr * 64 + i * 16 + fq * 4 + r;   // token within batch
        int col = n0 + wc * 64 + j * 16 + fr;
        float a = acc[i][j][r] * SCALE;
        int mk = mask[((size_t)b * SEQ + row) * SEQ + col];
        float rel = (mk != 0 && a > 0.f) ? a : 0.f;
        float Av = rel * rel / ll[b * SEQ + row];
        Abuf[((size_t)b * SEQ + row) * SEQ + col] = f2b(Av);
      }
}

__global__ __launch_bounds__(256) void k_av(const unsigned short* __restrict__ Abuf,
                                            const unsigned short* __restrict__ vT,
                                            const unsigned short* __restrict__ u,
                                            unsigned short* __restrict__ g) {
  __shared__ unsigned short ldsA[128 * 32], ldsB[128 * 32];
  int b = blockIdx.z;
  int m0 = blockIdx.x * 128, n0 = blockIdx.y * 128;
  f32x4 acc[4][4];
  mfma_tile_bt(Abuf + ((size_t)b * SEQ + m0) * SEQ, vT + ((size_t)b * UV + n0) * SEQ,
               SEQ, acc, ldsA, ldsB);
  EPILOGUE_COORDS();
#pragma unroll
  for (int i = 0; i < 4; ++i)
#pragma unroll
    for (int j = 0; j < 4; ++j)
#pragma unroll
      for (int r = 0; r < 4; ++r) {
        int row = m0 + wr * 64 + i * 16 + fq * 4 + r;
        int col = n0 + wc * 64 + j * 16 + fr;
        size_t gi = ((size_t)b * SEQ + row) * UV + col;
        g[gi] = f2b(acc[i][j][r] * b2f(u[gi]));
      }
}

__global__ __launch_bounds__(256) void k_out(const unsigned short* __restrict__ g,
                                             const unsigned short* __restrict__ WoT,
                                             const float* __restrict__ bo,
                                             float* __restrict__ out) {
  __shared__ unsigned short ldsA[128 * 32], ldsB[128 * 32];
  int m0 = blockIdx.x * 128, n0 = blockIdx.y * 128;
  f32x4 acc[4][4];
  mfma_tile_bt(g + (size_t)m0 * UV, WoT + (size_t)n0 * UV, UV, acc, ldsA, ldsB);
  EPILOGUE_COORDS();
#pragma unroll
  for (int i = 0; i < 4; ++i)
#pragma unroll
    for (int j = 0; j < 4; ++j)
#pragma unroll
      for (int r = 0; r < 4; ++r) {
        int row = m0 + wr * 64 + i * 16 + fq * 4 + r;
        int col = n0 + wc * 64 + j * 16 + fr;
        out[(size_t)row * DIM + col] = acc[i][j][r] + bo[col];
      }
}

// ---------------------------------------------------------------------------
extern "C" void kernel_launch(void* const* d_in, const int* in_sizes, int n_in,
                              void* d_out, int out_size, void* d_ws, size_t ws_size,
                              hipStream_t stream) {
  const float* h    = (const float*)d_in[0];
  const int*   mask = (const int*)d_in[1];
  const float* sn   = (const float*)d_in[2];
  const float* cs   = (const float*)d_in[3];
  const float* Wi   = (const float*)d_in[4];
  const float* bi   = (const float*)d_in[5];
  const float* Wo   = (const float*)d_in[6];
  const float* bo   = (const float*)d_in[7];
  const float* qg   = (const float*)d_in[8];
  const float* qb   = (const float*)d_in[9];
  const float* kg   = (const float*)d_in[10];
  const float* kb   = (const float*)d_in[11];
  float* out = (float*)d_out;

  char* ws = (char*)d_ws;
  size_t off = 0;
  auto alloc = [&](size_t bytes) { void* p = ws + off; off += (bytes + 255) & ~(size_t)255; return p; };
  unsigned short* hbf  = (unsigned short*)alloc((size_t)MTOT * DIM * 2);
  unsigned short* WiT  = (unsigned short*)alloc((size_t)NCOL * DIM * 2);
  unsigned short* WoT  = (unsigned short*)alloc((size_t)DIM * UV * 2);
  unsigned short* u    = (unsigned short*)alloc((size_t)MTOT * UV * 2);
  unsigned short* v    = (unsigned short*)alloc((size_t)MTOT * UV * 2);
  unsigned short* vT   = (unsigned short*)alloc((size_t)MTOT * UV * 2);
  float*          qkb  = (float*)alloc((size_t)MTOT * KEY * 4);
  unsigned short* qbuf = (unsigned short*)alloc((size_t)MTOT * KEY * 2);
  unsigned short* kbuf = (unsigned short*)alloc((size_t)MTOT * KEY * 2);
  float*          ll   = (float*)alloc((size_t)MTOT * 4);
  unsigned short* Abuf = (unsigned short*)alloc((size_t)BATCH * SEQ * SEQ * 2);
  unsigned short* g    = (unsigned short*)alloc((size_t)MTOT * UV * 2);

  k_cvt<<<(MTOT * DIM / 4) / 256, 256, 0, stream>>>(h, hbf);
  k_tcvt<<<dim3(NCOL / 32, DIM / 32), dim3(32, 8), 0, stream>>>(Wi, WiT, DIM, NCOL);
  k_tcvt<<<dim3(UV / 32, DIM / 32), dim3(32, 8), 0, stream>>>(Wo, WoT, DIM, UV);
  k_masksum<<<MTOT / 4, 256, 0, stream>>>(mask, ll);

  k_gemm1<<<dim3(MTOT / 128, NCOL / 128), 256, 0, stream>>>(hbf, WiT, bi, u, v, qkb);
  k_rope<<<(MTOT * 64) / 256, 256, 0, stream>>>(qkb, sn, cs, qg, qb, kg, kb, qbuf, kbuf);
  k_vT<<<dim3(SEQ / 64, UV / 64, BATCH), 256, 0, stream>>>(v, vT);
  k_qk<<<dim3(SEQ / 128, SEQ / 128, BATCH), 256, 0, stream>>>(qbuf, kbuf, mask, ll, Abuf);
  k_av<<<dim3(SEQ / 128, UV / 128, BATCH), 256, 0, stream>>>(Abuf, vT, u, g);
  k_out<<<dim3(MTOT / 128, DIM / 128), 256, 0, stream>>>(g, WoT, bo, out);
}